// Round 1
// baseline (318.387 us; speedup 1.0000x reference)
//
#include <hip/hip_runtime.h>

#define DIM    64      // CELL_DIM
#define NCELLS 512
#define CHUNK  256     // cells staged per LDS chunk
#define ROWS_PER_BLOCK 16
#define NROWS  8192

// Block: 256 threads = 4 waves. Wave w owns rows rowBase..rowBase+3.
// Lane l owns cells {ch*256 + 4l .. 4l+3} for each chunk ch -> 8 cells total.
// LDS: pcT[k][cell] transposed, XOR-swizzled (phys_quad = quad ^ (k>>2)) so
// both the transpose scatter-writes (2-way = free) and ds_read_b128 row reads
// are bank-conflict-free.
__global__ __launch_bounds__(256, 2)
void placecells_kernel(const float* __restrict__ x,
                       const float* __restrict__ pc,
                       float* __restrict__ out)
{
    __shared__ float pcT[DIM * CHUNK];   // 64 KB

    const int tid = (int)threadIdx.x;
    const int l   = tid & 63;
    // force wave id into an SGPR so all x addressing is provably uniform ->
    // compiler emits s_load_dwordx4 for the x tiles (keeps x off LDS/VMEM-vector)
    const int w   = __builtin_amdgcn_readfirstlane(tid >> 6);
    const int rowBase = (int)blockIdx.x * ROWS_PER_BLOCK + w * 4;

    float d[4][8];
    #pragma unroll
    for (int r = 0; r < 4; ++r)
        #pragma unroll
        for (int c = 0; c < 8; ++c) d[r][c] = 0.0f;

    #pragma unroll
    for (int ch = 0; ch < 2; ++ch) {
        if (ch) __syncthreads();
        // ---- stage chunk: global [cell][k] -> LDS pcT[k][cell], swizzled ----
        #pragma unroll
        for (int i = 0; i < 16; ++i) {
            int idx = i * 256 + tid;
            int cl  = idx >> 4;           // cell within chunk, 0..255
            int k4  = idx & 15;           // k-quad, 0..15  (coalesced 1KB/wave)
            float4 v = *(const float4*)(pc + (ch * CHUNK + cl) * DIM + k4 * 4);
            int cq = cl >> 2, cr = cl & 3;
            int pq = cq ^ k4;             // swizzle
            float* p = &pcT[(k4 * 4) * CHUNK + pq * 4 + cr];
            p[0 * CHUNK] = v.x;
            p[1 * CHUNK] = v.y;
            p[2 * CHUNK] = v.z;
            p[3 * CHUNK] = v.w;
        }
        __syncthreads();

        // ---- K loop: 4 rows x 4 cells x 4 k per iteration ----
        #pragma unroll
        for (int k4 = 0; k4 < 16; ++k4) {
            float4 xv[4];
            #pragma unroll
            for (int r = 0; r < 4; ++r)
                xv[r] = *(const float4*)(x + (rowBase + r) * DIM + k4 * 4);
            const int pq = (l ^ k4) * 4;  // undo swizzle: logical quad = l
            #pragma unroll
            for (int j = 0; j < 4; ++j) {
                float4 pv = *(const float4*)(&pcT[(k4 * 4 + j) * CHUNK + pq]);
                #pragma unroll
                for (int r = 0; r < 4; ++r) {
                    float xk = (j == 0) ? xv[r].x : (j == 1) ? xv[r].y
                             : (j == 2) ? xv[r].z : xv[r].w;
                    d[r][ch * 4 + 0] += fabsf(xk - pv.x);
                    d[r][ch * 4 + 1] += fabsf(xk - pv.y);
                    d[r][ch * 4 + 2] += fabsf(xk - pv.z);
                    d[r][ch * 4 + 3] += fabsf(xk - pv.w);
                }
            }
        }
    }

    // ---- softmax per row over 512 cells (one wave holds a whole row) ----
    #pragma unroll
    for (int r = 0; r < 4; ++r) {
        // min L1 distance == min d^2 (d >= 0) -> stable max-subtraction
        float mn = d[r][0];
        #pragma unroll
        for (int c = 1; c < 8; ++c) mn = fminf(mn, d[r][c]);
        #pragma unroll
        for (int off = 32; off > 0; off >>= 1)
            mn = fminf(mn, __shfl_xor(mn, off, 64));
        float m2 = mn * mn;

        float e[8], s = 0.0f;
        #pragma unroll
        for (int c = 0; c < 8; ++c) {
            float dd = d[r][c];
            e[c] = __expf(0.5f * (m2 - dd * dd));   // arg <= 0, no overflow
            s += e[c];
        }
        #pragma unroll
        for (int off = 32; off > 0; off >>= 1)
            s += __shfl_xor(s, off, 64);
        float inv = 1.0f / s;

        float* orow = out + (size_t)(rowBase + r) * NCELLS;
        float4 o0 = make_float4(e[0] * inv, e[1] * inv, e[2] * inv, e[3] * inv);
        float4 o1 = make_float4(e[4] * inv, e[5] * inv, e[6] * inv, e[7] * inv);
        *(float4*)(orow + 4 * l)         = o0;
        *(float4*)(orow + CHUNK + 4 * l) = o1;
    }
}

extern "C" void kernel_launch(void* const* d_in, const int* in_sizes, int n_in,
                              void* d_out, int out_size, void* d_ws, size_t ws_size,
                              hipStream_t stream)
{
    const float* x  = (const float*)d_in[0];   // (8192, 64) fp32
    const float* pc = (const float*)d_in[1];   // (512, 64) fp32
    float* out = (float*)d_out;                // (8192, 512) fp32
    placecells_kernel<<<dim3(NROWS / ROWS_PER_BLOCK), dim3(256), 0, stream>>>(x, pc, out);
}

// Round 2
// 81.269 us; speedup vs baseline: 3.9177x; 3.9177x over previous
//
#include <hip/hip_runtime.h>

#define DIM    64      // CELL_DIM
#define NCELLS 512
#define CHUNK  256     // cells staged per LDS chunk
#define ROWS_PER_BLOCK 16
#define NROWS  8192

// Block: 256 threads = 4 waves. Wave w owns rows rowBase..rowBase+3.
// Lane l owns cells {ch*256 + 4l .. 4l+3} per chunk ch.
// Accumulators are named float4s (NOT arrays) — R1 showed local arrays with
// loop-variable indices land in scratch (800 MB of HBM spill traffic).
__global__ __launch_bounds__(256, 2)
void placecells_kernel(const float* __restrict__ x,
                       const float* __restrict__ pc,
                       float* __restrict__ out)
{
    __shared__ float pcT[DIM * CHUNK];   // 64 KB, [k][cell] XOR-swizzled

    const int tid = (int)threadIdx.x;
    const int l   = tid & 63;
    const int w   = __builtin_amdgcn_readfirstlane(tid >> 6);
    const int rowBase = (int)blockIdx.x * ROWS_PER_BLOCK + w * 4;

    // d{row}{chunk}: 4 cells each -> 32 accumulator VGPRs, promotion-safe
    float4 d00{0,0,0,0}, d10{0,0,0,0}, d20{0,0,0,0}, d30{0,0,0,0};
    float4 d01{0,0,0,0}, d11{0,0,0,0}, d21{0,0,0,0}, d31{0,0,0,0};

    auto do_chunk = [&](int ch, float4& a0, float4& a1, float4& a2, float4& a3) {
        // ---- stage chunk: global [cell][k] -> LDS pcT[k][cell], swizzled ----
        #pragma unroll 4
        for (int i = 0; i < 16; ++i) {
            int idx = i * 256 + tid;
            int cl  = idx >> 4;           // cell within chunk, 0..255
            int k4  = idx & 15;           // k-quad (coalesced 1KB/wave)
            float4 v = *(const float4*)(pc + (ch * CHUNK + cl) * DIM + k4 * 4);
            int pq = (cl >> 2) ^ k4;      // bank swizzle
            float* p = &pcT[(k4 * 4) * CHUNK + pq * 4 + (cl & 3)];
            p[0 * CHUNK] = v.x;
            p[1 * CHUNK] = v.y;
            p[2 * CHUNK] = v.z;
            p[3 * CHUNK] = v.w;
        }
        __syncthreads();

        // ---- K loop: 4 rows x 4 cells x 4 k per iteration ----
        #pragma unroll 4
        for (int k4 = 0; k4 < 16; ++k4) {
            float4 xv0 = *(const float4*)(x + (rowBase + 0) * DIM + k4 * 4);
            float4 xv1 = *(const float4*)(x + (rowBase + 1) * DIM + k4 * 4);
            float4 xv2 = *(const float4*)(x + (rowBase + 2) * DIM + k4 * 4);
            float4 xv3 = *(const float4*)(x + (rowBase + 3) * DIM + k4 * 4);
            const int pq4 = (l ^ k4) * 4; // undo swizzle: logical quad = l
            #pragma unroll
            for (int j = 0; j < 4; ++j) {
                float4 pv = *(const float4*)(&pcT[(k4 * 4 + j) * CHUNK + pq4]);
                float x0 = (j == 0) ? xv0.x : (j == 1) ? xv0.y : (j == 2) ? xv0.z : xv0.w;
                float x1 = (j == 0) ? xv1.x : (j == 1) ? xv1.y : (j == 2) ? xv1.z : xv1.w;
                float x2 = (j == 0) ? xv2.x : (j == 1) ? xv2.y : (j == 2) ? xv2.z : xv2.w;
                float x3 = (j == 0) ? xv3.x : (j == 1) ? xv3.y : (j == 2) ? xv3.z : xv3.w;
                a0.x += fabsf(x0 - pv.x); a0.y += fabsf(x0 - pv.y);
                a0.z += fabsf(x0 - pv.z); a0.w += fabsf(x0 - pv.w);
                a1.x += fabsf(x1 - pv.x); a1.y += fabsf(x1 - pv.y);
                a1.z += fabsf(x1 - pv.z); a1.w += fabsf(x1 - pv.w);
                a2.x += fabsf(x2 - pv.x); a2.y += fabsf(x2 - pv.y);
                a2.z += fabsf(x2 - pv.z); a2.w += fabsf(x2 - pv.w);
                a3.x += fabsf(x3 - pv.x); a3.y += fabsf(x3 - pv.y);
                a3.z += fabsf(x3 - pv.z); a3.w += fabsf(x3 - pv.w);
            }
        }
    };

    do_chunk(0, d00, d10, d20, d30);
    __syncthreads();
    do_chunk(1, d01, d11, d21, d31);

    // ---- softmax per row over 512 cells (one wave holds a whole row) ----
    auto finish_row = [&](float4 a, float4 b, int r) {
        // min L1 == min d^2 (d >= 0) -> exact max-subtraction
        float mn = fminf(fminf(fminf(a.x, a.y), fminf(a.z, a.w)),
                         fminf(fminf(b.x, b.y), fminf(b.z, b.w)));
        #pragma unroll
        for (int off = 32; off > 0; off >>= 1)
            mn = fminf(mn, __shfl_xor(mn, off, 64));
        float m2 = mn * mn;

        float e0 = __expf(0.5f * (m2 - a.x * a.x));
        float e1 = __expf(0.5f * (m2 - a.y * a.y));
        float e2 = __expf(0.5f * (m2 - a.z * a.z));
        float e3 = __expf(0.5f * (m2 - a.w * a.w));
        float e4 = __expf(0.5f * (m2 - b.x * b.x));
        float e5 = __expf(0.5f * (m2 - b.y * b.y));
        float e6 = __expf(0.5f * (m2 - b.z * b.z));
        float e7 = __expf(0.5f * (m2 - b.w * b.w));
        float s = ((e0 + e1) + (e2 + e3)) + ((e4 + e5) + (e6 + e7));
        #pragma unroll
        for (int off = 32; off > 0; off >>= 1)
            s += __shfl_xor(s, off, 64);
        float inv = 1.0f / s;

        float* orow = out + (size_t)(rowBase + r) * NCELLS;
        *(float4*)(orow + 4 * l)         = make_float4(e0 * inv, e1 * inv, e2 * inv, e3 * inv);
        *(float4*)(orow + CHUNK + 4 * l) = make_float4(e4 * inv, e5 * inv, e6 * inv, e7 * inv);
    };
    finish_row(d00, d01, 0);
    finish_row(d10, d11, 1);
    finish_row(d20, d21, 2);
    finish_row(d30, d31, 3);
}

extern "C" void kernel_launch(void* const* d_in, const int* in_sizes, int n_in,
                              void* d_out, int out_size, void* d_ws, size_t ws_size,
                              hipStream_t stream)
{
    const float* x  = (const float*)d_in[0];   // (8192, 64) fp32
    const float* pc = (const float*)d_in[1];   // (512, 64) fp32
    float* out = (float*)d_out;                // (8192, 512) fp32
    placecells_kernel<<<dim3(NROWS / ROWS_PER_BLOCK), dim3(256), 0, stream>>>(x, pc, out);
}